// Round 1
// baseline (375.312 us; speedup 1.0000x reference)
//
#include <hip/hip_runtime.h>
#include <hip/hip_bf16.h>

#define BB 128
#define UU 200
#define DD 512
#define NPAD 256
#define ASTR 40   // LDS row stride (bf16 elems): 32 data + 8 pad, 80 B, 16B-aligned
#define WSTR 40

typedef __attribute__((ext_vector_type(8))) short short8;
typedef __attribute__((ext_vector_type(4))) float f32x4;

__device__ __forceinline__ unsigned short f2bf(float x) {
    union { float f; unsigned u; } v; v.f = x;
    unsigned r = v.u + 0x7FFFu + ((v.u >> 16) & 1u);
    return (unsigned short)(r >> 16);
}

__global__ void zero_out_kernel(float* __restrict__ out) {
    int i = blockIdx.x * 256 + threadIdx.x;
    if (i < BB * UU) out[i] = 0.0f;
}

__global__ __launch_bounds__(512, 4) void cm_gemm_kernel(
    const float* __restrict__ Ar, const float* __restrict__ Ai,
    const float* __restrict__ Kt, float* __restrict__ out)
{
    __shared__ short sAr[BB * ASTR];
    __shared__ short sAi[BB * ASTR];
    __shared__ short sWr[NPAD * WSTR];
    __shared__ short sWi[NPAD * WSTR];

    const int tid  = threadIdx.x;
    const int irow = blockIdx.x;          // i-row of A handled by this block (split-K)
    const int w    = tid >> 6;            // wave 0..7
    const int lane = tid & 63;
    const int mw   = (w & 1) * 64;        // wave m-offset (2 along M)
    const int nw   = (w >> 1) * 64;       // wave n-offset (4 along N)
    const int rrow = lane & 15;
    const int quad = lane >> 4;

    // ---- W-synthesis assignment: thread -> (n, j-half) ----
    const int nW = tid >> 1;              // 0..255
    const int jh = (tid & 1) * 16;        // 0 or 16
    float krI = 0.0f, kiI = 0.0f;
    if (nW < UU) {
        const float2* k2 = (const float2*)Kt;   // (kr, ki) interleaved per (n,d)
        float2 s = k2[(size_t)nW * DD + irow];
        krI = s.x; kiI = s.y;
    }

    // ---- A staging assignment: thread -> 2 float4 groups ----
    const int brow0 = tid >> 3;           // 0..63
    const int grp   = tid & 7;            // 8 float4 groups of 32 floats
    const size_t aoff0 = (size_t)brow0 * DD * DD + (size_t)irow * DD + (size_t)grp * 4;
    const size_t aoff1 = aoff0 + (size_t)64 * DD * DD;

    f32x4 acc[4][4];
#pragma unroll
    for (int a = 0; a < 4; ++a)
#pragma unroll
        for (int b = 0; b < 4; ++b) acc[a][b] = (f32x4)(0.0f);

    for (int jw = 0; jw < DD; jw += 32) {
        // ---- stage A_r / A_i tile (128 x 32 fp32 -> bf16 LDS) ----
        f32x4 vr0 = *(const f32x4*)(Ar + aoff0 + jw);
        f32x4 vr1 = *(const f32x4*)(Ar + aoff1 + jw);
        f32x4 vi0 = *(const f32x4*)(Ai + aoff0 + jw);
        f32x4 vi1 = *(const f32x4*)(Ai + aoff1 + jw);

        {
            union { unsigned short s[4]; uint2 u; } t0, t1, t2, t3;
#pragma unroll
            for (int q = 0; q < 4; ++q) {
                t0.s[q] = f2bf(vr0[q]); t1.s[q] = f2bf(vr1[q]);
                t2.s[q] = f2bf(vi0[q]); t3.s[q] = f2bf(vi1[q]);
            }
            *(uint2*)&sAr[ brow0       * ASTR + grp * 4] = t0.u;
            *(uint2*)&sAr[(brow0 + 64) * ASTR + grp * 4] = t1.u;
            *(uint2*)&sAi[ brow0       * ASTR + grp * 4] = t2.u;
            *(uint2*)&sAi[(brow0 + 64) * ASTR + grp * 4] = t3.u;
        }

        // ---- synthesize W_r / W_i tile (256 x 32 bf16) ----
        if (nW < UU) {
            const f32x4* kv = (const f32x4*)(Kt + (size_t)nW * DD * 2 + (size_t)(jw + jh) * 2);
#pragma unroll
            for (int q = 0; q < 8; ++q) {
                f32x4 v = kv[q];  // {kr(j0), ki(j0), kr(j1), ki(j1)}
                float wr0 =  krI * v[0] - kiI * v[1];
                float wi0 = -(krI * v[1] + kiI * v[0]);
                float wr1 =  krI * v[2] - kiI * v[3];
                float wi1 = -(krI * v[3] + kiI * v[2]);
                unsigned pr = (unsigned)f2bf(wr0) | ((unsigned)f2bf(wr1) << 16);
                unsigned pi = (unsigned)f2bf(wi0) | ((unsigned)f2bf(wi1) << 16);
                *(unsigned*)&sWr[nW * WSTR + jh + 2 * q] = pr;
                *(unsigned*)&sWi[nW * WSTR + jh + 2 * q] = pi;
            }
        } else {
#pragma unroll
            for (int q = 0; q < 8; ++q) {
                *(unsigned*)&sWr[nW * WSTR + jh + 2 * q] = 0u;
                *(unsigned*)&sWi[nW * WSTR + jh + 2 * q] = 0u;
            }
        }

        __syncthreads();

        // ---- MFMA: both phases accumulate into the same C ----
#pragma unroll
        for (int ph = 0; ph < 2; ++ph) {
            const short* sA = ph ? sAi : sAr;
            const short* sW = ph ? sWi : sWr;
            short8 af[4], bf[4];
#pragma unroll
            for (int t = 0; t < 4; ++t) {
                af[t] = *(const short8*)&sA[(mw + t * 16 + rrow) * ASTR + quad * 8];
                bf[t] = *(const short8*)&sW[(nw + t * 16 + rrow) * WSTR + quad * 8];
            }
#pragma unroll
            for (int ti = 0; ti < 4; ++ti)
#pragma unroll
                for (int tj = 0; tj < 4; ++tj)
                    acc[ti][tj] = __builtin_amdgcn_mfma_f32_16x16x32_bf16(
                        af[ti], bf[tj], acc[ti][tj], 0, 0, 0);
        }

        __syncthreads();
    }

    // ---- epilogue: split-K partials via fp32 atomics ----
#pragma unroll
    for (int ti = 0; ti < 4; ++ti) {
        int m = mw + ti * 16 + quad * 4;
#pragma unroll
        for (int tj = 0; tj < 4; ++tj) {
            int n = nw + tj * 16 + rrow;
            if (n < UU) {
#pragma unroll
                for (int r = 0; r < 4; ++r)
                    atomicAdd(&out[(size_t)(m + r) * UU + n], acc[ti][tj][r]);
            }
        }
    }
}

extern "C" void kernel_launch(void* const* d_in, const int* in_sizes, int n_in,
                              void* d_out, int out_size, void* d_ws, size_t ws_size,
                              hipStream_t stream) {
    const float* Ar = (const float*)d_in[0];
    const float* Ai = (const float*)d_in[1];
    const float* Kt = (const float*)d_in[2];
    float* out = (float*)d_out;

    hipLaunchKernelGGL(zero_out_kernel, dim3((BB * UU + 255) / 256), dim3(256), 0, stream, out);
    hipLaunchKernelGGL(cm_gemm_kernel, dim3(DD), dim3(512), 0, stream, Ar, Ai, Kt, out);
}

// Round 2
// 322.184 us; speedup vs baseline: 1.1649x; 1.1649x over previous
//
#include <hip/hip_runtime.h>
#include <hip/hip_bf16.h>

#define BB 128
#define UU 200
#define DD 512
#define NPAD 256
#define ASTR 40   // LDS row stride (bf16 elems): 32 data + 8 pad, 80 B, 16B-aligned
#define WSTR 40
#define NSPLIT 512   // split-K factor = grid size of GEMM

typedef __attribute__((ext_vector_type(8))) short short8;
typedef __attribute__((ext_vector_type(4))) float f32x4;

__device__ __forceinline__ unsigned short f2bf(float x) {
    union { float f; unsigned u; } v; v.f = x;
    unsigned r = v.u + 0x7FFFu + ((v.u >> 16) & 1u);
    return (unsigned short)(r >> 16);
}

__global__ void zero_out_kernel(float* __restrict__ out) {
    int i = blockIdx.x * 256 + threadIdx.x;
    if (i < BB * UU) out[i] = 0.0f;
}

// Sum 512 partials: grid (100, 8); each block-row sums a 64-partial chunk,
// then one atomicAdd per (chunk, output) -> 8*25600 = 205k atomics, trivial.
__global__ void reduce_kernel(const float* __restrict__ ws, float* __restrict__ out) {
    int o = blockIdx.x * 256 + threadIdx.x;
    if (o >= BB * UU) return;
    int p0 = blockIdx.y * (NSPLIT / 8);
    float s = 0.0f;
#pragma unroll 8
    for (int p = 0; p < NSPLIT / 8; ++p)
        s += ws[(size_t)(p0 + p) * (BB * UU) + o];
    atomicAdd(&out[o], s);
}

template<bool USE_WS>
__global__ __launch_bounds__(512, 4) void cm_gemm_kernel(
    const float* __restrict__ Ar, const float* __restrict__ Ai,
    const float* __restrict__ Kt, float* __restrict__ dst)
{
    __shared__ short sAr[BB * ASTR];
    __shared__ short sAi[BB * ASTR];
    __shared__ short sWr[NPAD * WSTR];
    __shared__ short sWi[NPAD * WSTR];

    const int tid  = threadIdx.x;
    const int irow = blockIdx.x;          // i-row of A handled by this block (split-K)
    const int w    = tid >> 6;            // wave 0..7
    const int lane = tid & 63;
    const int mw   = (w & 1) * 64;        // wave m-offset (2 along M)
    const int nw   = (w >> 1) * 64;       // wave n-offset (4 along N)
    const int rrow = lane & 15;
    const int quad = lane >> 4;

    // ---- W-synthesis assignment: thread -> (n, j-half) ----
    const int nW = tid >> 1;              // 0..255
    const int jh = (tid & 1) * 16;        // 0 or 16
    float krI = 0.0f, kiI = 0.0f;
    if (nW < UU) {
        const float2* k2 = (const float2*)Kt;   // (kr, ki) interleaved per (n,d)
        float2 s = k2[(size_t)nW * DD + irow];
        krI = s.x; kiI = s.y;
    }

    // ---- A staging assignment: thread -> 2 float4 groups ----
    const int brow0 = tid >> 3;           // 0..63
    const int grp   = tid & 7;            // 8 float4 groups of 32 floats
    const size_t aoff0 = (size_t)brow0 * DD * DD + (size_t)irow * DD + (size_t)grp * 4;
    const size_t aoff1 = aoff0 + (size_t)64 * DD * DD;

    f32x4 acc[4][4];
#pragma unroll
    for (int a = 0; a < 4; ++a)
#pragma unroll
        for (int b = 0; b < 4; ++b) acc[a][b] = (f32x4)(0.0f);

    // ---- prefetch iter 0 A tiles into registers ----
    f32x4 vr0 = *(const f32x4*)(Ar + aoff0);
    f32x4 vr1 = *(const f32x4*)(Ar + aoff1);
    f32x4 vi0 = *(const f32x4*)(Ai + aoff0);
    f32x4 vi1 = *(const f32x4*)(Ai + aoff1);

    for (int it = 0; it < 16; ++it) {
        const int jw = it * 32;

        // ---- convert current A regs -> bf16 LDS ----
        {
            union { unsigned short s[4]; uint2 u; } t0, t1, t2, t3;
#pragma unroll
            for (int q = 0; q < 4; ++q) {
                t0.s[q] = f2bf(vr0[q]); t1.s[q] = f2bf(vr1[q]);
                t2.s[q] = f2bf(vi0[q]); t3.s[q] = f2bf(vi1[q]);
            }
            *(uint2*)&sAr[ brow0       * ASTR + grp * 4] = t0.u;
            *(uint2*)&sAr[(brow0 + 64) * ASTR + grp * 4] = t1.u;
            *(uint2*)&sAi[ brow0       * ASTR + grp * 4] = t2.u;
            *(uint2*)&sAi[(brow0 + 64) * ASTR + grp * 4] = t3.u;
        }

        // ---- synthesize W_r / W_i tile (256 x 32 bf16) ----
        if (nW < UU) {
            const f32x4* kv = (const f32x4*)(Kt + (size_t)nW * DD * 2 + (size_t)(jw + jh) * 2);
#pragma unroll
            for (int q = 0; q < 8; ++q) {
                f32x4 v = kv[q];  // {kr(j0), ki(j0), kr(j1), ki(j1)}
                float wr0 =  krI * v[0] - kiI * v[1];
                float wi0 = -(krI * v[1] + kiI * v[0]);
                float wr1 =  krI * v[2] - kiI * v[3];
                float wi1 = -(krI * v[3] + kiI * v[2]);
                unsigned pr = (unsigned)f2bf(wr0) | ((unsigned)f2bf(wr1) << 16);
                unsigned pi = (unsigned)f2bf(wi0) | ((unsigned)f2bf(wi1) << 16);
                *(unsigned*)&sWr[nW * WSTR + jh + 2 * q] = pr;
                *(unsigned*)&sWi[nW * WSTR + jh + 2 * q] = pi;
            }
        } else {
#pragma unroll
            for (int q = 0; q < 8; ++q) {
                *(unsigned*)&sWr[nW * WSTR + jh + 2 * q] = 0u;
                *(unsigned*)&sWi[nW * WSTR + jh + 2 * q] = 0u;
            }
        }

        __syncthreads();

        // ---- issue next iter's A loads (overlap with MFMA below) ----
        const int jn = (it < 15) ? (jw + 32) : 0;
        f32x4 nr0 = *(const f32x4*)(Ar + aoff0 + jn);
        f32x4 nr1 = *(const f32x4*)(Ar + aoff1 + jn);
        f32x4 ni0 = *(const f32x4*)(Ai + aoff0 + jn);
        f32x4 ni1 = *(const f32x4*)(Ai + aoff1 + jn);

        // ---- MFMA: both phases accumulate into the same C ----
#pragma unroll
        for (int ph = 0; ph < 2; ++ph) {
            const short* sA = ph ? sAi : sAr;
            const short* sW = ph ? sWi : sWr;
            short8 af[4], bf[4];
#pragma unroll
            for (int t = 0; t < 4; ++t) {
                af[t] = *(const short8*)&sA[(mw + t * 16 + rrow) * ASTR + quad * 8];
                bf[t] = *(const short8*)&sW[(nw + t * 16 + rrow) * WSTR + quad * 8];
            }
#pragma unroll
            for (int ti = 0; ti < 4; ++ti)
#pragma unroll
                for (int tj = 0; tj < 4; ++tj)
                    acc[ti][tj] = __builtin_amdgcn_mfma_f32_16x16x32_bf16(
                        af[ti], bf[tj], acc[ti][tj], 0, 0, 0);
        }

        __syncthreads();

        vr0 = nr0; vr1 = nr1; vi0 = ni0; vi1 = ni1;
    }

    // ---- epilogue ----
    if (USE_WS) {
        // plain coalesced stores of this block's partial into ws[irow][m][n]
        float* wsp = dst + (size_t)irow * (BB * UU);
#pragma unroll
        for (int ti = 0; ti < 4; ++ti) {
            int m = mw + ti * 16 + quad * 4;
#pragma unroll
            for (int tj = 0; tj < 4; ++tj) {
                int n = nw + tj * 16 + rrow;
                if (n < UU) {
#pragma unroll
                    for (int r = 0; r < 4; ++r)
                        wsp[(size_t)(m + r) * UU + n] = acc[ti][tj][r];
                }
            }
        }
    } else {
#pragma unroll
        for (int ti = 0; ti < 4; ++ti) {
            int m = mw + ti * 16 + quad * 4;
#pragma unroll
            for (int tj = 0; tj < 4; ++tj) {
                int n = nw + tj * 16 + rrow;
                if (n < UU) {
#pragma unroll
                    for (int r = 0; r < 4; ++r)
                        atomicAdd(&dst[(size_t)(m + r) * UU + n], acc[ti][tj][r]);
                }
            }
        }
    }
}

extern "C" void kernel_launch(void* const* d_in, const int* in_sizes, int n_in,
                              void* d_out, int out_size, void* d_ws, size_t ws_size,
                              hipStream_t stream) {
    const float* Ar = (const float*)d_in[0];
    const float* Ai = (const float*)d_in[1];
    const float* Kt = (const float*)d_in[2];
    float* out = (float*)d_out;

    const size_t ws_need = (size_t)NSPLIT * BB * UU * sizeof(float);  // 52.4 MB

    if (ws_size >= ws_need) {
        float* ws = (float*)d_ws;
        hipLaunchKernelGGL((cm_gemm_kernel<true>), dim3(NSPLIT), dim3(512), 0, stream,
                           Ar, Ai, Kt, ws);
        hipLaunchKernelGGL(zero_out_kernel, dim3((BB * UU + 255) / 256), dim3(256), 0, stream, out);
        hipLaunchKernelGGL(reduce_kernel, dim3((BB * UU + 255) / 256, 8), dim3(256), 0, stream,
                           ws, out);
    } else {
        hipLaunchKernelGGL(zero_out_kernel, dim3((BB * UU + 255) / 256), dim3(256), 0, stream, out);
        hipLaunchKernelGGL((cm_gemm_kernel<false>), dim3(NSPLIT), dim3(512), 0, stream,
                           Ar, Ai, Kt, out);
    }
}

// Round 3
// 306.271 us; speedup vs baseline: 1.2254x; 1.0520x over previous
//
#include <hip/hip_runtime.h>
#include <hip/hip_bf16.h>
#include <string.h>

#define BB 128
#define UU 200
#define DD 512
#define NP 256
#define NWS 504   // blocks 0..503 write ws slices; 504..511 atomicAdd into out

typedef __attribute__((ext_vector_type(8))) short short8;
typedef __attribute__((ext_vector_type(4))) float f32x4;

__device__ __forceinline__ unsigned pack_bf16_2(float a, float b) {
    __hip_bfloat162 h = __float22bfloat162_rn(make_float2(a, b));
    unsigned u; memcpy(&u, &h, 4); return u;
}

__device__ __forceinline__ unsigned short f2bf(float x) {
    union { float f; unsigned u; } v; v.f = x;
    unsigned r = v.u + 0x7FFFu + ((v.u >> 16) & 1u);
    return (unsigned short)(r >> 16);
}

// ---- build packed bf16 kernel table: Kb[n*512+j] = bf16(kr)|bf16(ki)<<16, zero for n>=200
__global__ void kb_build_kernel(const float* __restrict__ Kt, unsigned* __restrict__ Kb) {
    int idx = blockIdx.x * 256 + threadIdx.x;    // 0..131071 (256 n x 512 j)
    int n = idx >> 9, j = idx & 511;
    unsigned v = 0u;
    if (n < UU) {
        float2 s = ((const float2*)Kt)[(size_t)n * DD + j];
        v = pack_bf16_2(s.x, s.y);
    }
    Kb[idx] = v;
}

__global__ void zero_out_kernel(float* __restrict__ out) {
    int i = blockIdx.x * 256 + threadIdx.x;
    if (i < BB * UU) out[i] = 0.0f;
}

// ---- sum the 504 ws partials into out (out pre-zeroed; blocks 504..511 atomic'd in gemm)
__global__ void reduce_kernel(const float* __restrict__ ws, float* __restrict__ out) {
    int o = blockIdx.x * 256 + threadIdx.x;
    if (o >= BB * UU) return;
    int p0 = blockIdx.y * 36;                     // grid.y = 14, 14*36 = 504
    float s = 0.0f;
#pragma unroll
    for (int p = 0; p < 36; ++p)
        s += ws[(size_t)(p0 + p) * (BB * UU) + o];
    atomicAdd(&out[o], s);
}

// ---- main GEMM: block = one i-row, tile M=128 x N=256, BK=128 phase-split dbuf
__global__ __launch_bounds__(1024, 4) void cm_gemm2_kernel(
    const float* __restrict__ Ar, const float* __restrict__ Ai,
    const float* __restrict__ Kt, const unsigned* __restrict__ Kb,
    float* __restrict__ ws, float* __restrict__ out)
{
    __shared__ short sA[2 * 128 * 128];   // 2 x 32 KB, XOR-swizzled, no pad

    const int tid  = threadIdx.x;
    const int irow = blockIdx.x;
    const int w    = tid >> 6;
    const int lane = tid & 63;
    const int rrow = lane & 15;
    const int quad = lane >> 4;
    const int nn   = w * 16 + rrow;       // this lane's output column (wave-disjoint n-slices)
    const int xr   = rrow & 7;

    float krI = 0.f, kiI = 0.f;
    if (nn < UU) {
        float2 s = ((const float2*)Kt)[(size_t)nn * DD + irow];
        krI = s.x; kiI = s.y;
    }
    const float nkrI = -krI, nkiI = -kiI;

    // A staging: lane loads 4 rows (b = r0+32l), float-group g -> 512B contiguous per 32 lanes
    const int g = tid & 31, r0 = tid >> 5;
    unsigned boff[4];
    int waddr[4];
#pragma unroll
    for (int l = 0; l < 4; ++l) {
        int row = r0 + 32 * l;
        boff[l] = (unsigned)row * (DD * DD) + (unsigned)irow * DD + g * 4;
        waddr[l] = row * 128 + (((g >> 1) ^ (row & 7)) * 8) + (g & 1) * 4;
    }

    f32x4 acc[8];
#pragma unroll
    for (int t = 0; t < 8; ++t) acc[t] = (f32x4)(0.f);

    // prefetch sub-stage 0 (Ar, j0 = 0)
    f32x4 pf[4];
#pragma unroll
    for (int l = 0; l < 4; ++l) pf[l] = *(const f32x4*)(Ar + boff[l]);

    short8 bi_sv[4];   // imag-phase B fragments, computed at ph=0, used at ph=1

    for (int t = 0; t < 8; ++t) {         // sub-stage: s = t>>1 (j-chunk), ph = t&1
        const int ph = t & 1;
        const int j0 = (t >> 1) * 128;
        short* sb = &sA[(t & 1) * (128 * 128)];

        // convert prefetched fp32 -> bf16 LDS (swizzled)
#pragma unroll
        for (int l = 0; l < 4; ++l) {
            uint2 u;
            u.x = pack_bf16_2(pf[l][0], pf[l][1]);
            u.y = pack_bf16_2(pf[l][2], pf[l][3]);
            *(uint2*)&sb[waddr[l]] = u;
        }
        __syncthreads();   // clean drain: nothing outstanding here

        // issue next sub-stage's global loads (fly during MFMA below)
        if (t < 7) {
            const int tn = t + 1;
            const float* P = (tn & 1) ? Ai : Ar;
            const unsigned jn = (unsigned)((tn >> 1) * 128);
#pragma unroll
            for (int l = 0; l < 4; ++l) pf[l] = *(const f32x4*)(P + boff[l] + jn);
        }

        const unsigned* kbp = Kb + (unsigned)nn * DD + j0 + quad * 8;
        uint4 nx0, nx1;
        if (ph == 0) { nx0 = *(const uint4*)kbp; nx1 = *(const uint4*)(kbp + 4); }

#pragma unroll
        for (int kk = 0; kk < 4; ++kk) {
            short8 bfrag;
            if (ph == 0) {
                uint4 c0 = nx0, c1 = nx1;
                if (kk < 3) {
                    nx0 = *(const uint4*)(kbp + (kk + 1) * 32);
                    nx1 = *(const uint4*)(kbp + (kk + 1) * 32 + 4);
                }
                unsigned dw[8] = {c0.x, c0.y, c0.z, c0.w, c1.x, c1.y, c1.z, c1.w};
                float wr[8], wi[8];
#pragma unroll
                for (int e = 0; e < 8; ++e) {
                    union { unsigned u; float f; } a, b;
                    a.u = dw[e] << 16;           // kr (lo16) as f32
                    b.u = dw[e] & 0xFFFF0000u;   // ki (hi16) as f32
                    wr[e] = krI * a.f + nkiI * b.f;
                    wi[e] = nkrI * b.f + nkiI * a.f;
                }
                union { short8 v; unsigned u[4]; } pr, pi;
#pragma unroll
                for (int e = 0; e < 4; ++e) {
                    pr.u[e] = pack_bf16_2(wr[2 * e], wr[2 * e + 1]);
                    pi.u[e] = pack_bf16_2(wi[2 * e], wi[2 * e + 1]);
                }
                bfrag = pr.v;
                bi_sv[kk] = pi.v;
            } else {
                bfrag = bi_sv[kk];
            }

#pragma unroll
            for (int h = 0; h < 2; ++h) {
                short8 af[4];
#pragma unroll
                for (int q = 0; q < 4; ++q) {
                    int row = (h * 4 + q) * 16 + rrow;
                    int gran = (kk * 4 + quad) ^ xr;
                    af[q] = *(const short8*)&sb[row * 128 + gran * 8];
                }
#pragma unroll
                for (int q = 0; q < 4; ++q)
                    acc[h * 4 + q] = __builtin_amdgcn_mfma_f32_16x16x32_bf16(
                        af[q], bfrag, acc[h * 4 + q], 0, 0, 0);
            }
        }
    }

    // ---- epilogue: plain stores of split-K partials (atomics only for last 8 blocks)
    if (nn < UU) {
        if (irow < NWS) {
            float* wsp = ws + (size_t)irow * (BB * UU);
#pragma unroll
            for (int ti = 0; ti < 8; ++ti) {
                int m = ti * 16 + quad * 4;
#pragma unroll
                for (int r = 0; r < 4; ++r)
                    wsp[(size_t)(m + r) * UU + nn] = acc[ti][r];
            }
        } else {
#pragma unroll
            for (int ti = 0; ti < 8; ++ti) {
                int m = ti * 16 + quad * 4;
#pragma unroll
                for (int r = 0; r < 4; ++r)
                    atomicAdd(&out[(size_t)(m + r) * UU + nn], acc[ti][r]);
            }
        }
    }
}

// ---- fallback (ws too small): R2's atomic kernel, f32 Kt synthesis in LDS
#define ASTR 40
#define WSTR 40
__global__ __launch_bounds__(512, 4) void cm_gemm_fb_kernel(
    const float* __restrict__ Ar, const float* __restrict__ Ai,
    const float* __restrict__ Kt, float* __restrict__ dst)
{
    __shared__ short sAr[BB * ASTR];
    __shared__ short sAi[BB * ASTR];
    __shared__ short sWr[NP * WSTR];
    __shared__ short sWi[NP * WSTR];
    const int tid = threadIdx.x, irow = blockIdx.x;
    const int w = tid >> 6, lane = tid & 63;
    const int mw = (w & 1) * 64, nw = (w >> 1) * 64;
    const int rrow = lane & 15, quad = lane >> 4;
    const int nW = tid >> 1, jh = (tid & 1) * 16;
    float krI = 0.f, kiI = 0.f;
    if (nW < UU) { float2 s = ((const float2*)Kt)[(size_t)nW * DD + irow]; krI = s.x; kiI = s.y; }
    const int brow0 = tid >> 3, grp = tid & 7;
    const size_t aoff0 = (size_t)brow0 * DD * DD + (size_t)irow * DD + (size_t)grp * 4;
    const size_t aoff1 = aoff0 + (size_t)64 * DD * DD;
    f32x4 acc[4][4];
#pragma unroll
    for (int a = 0; a < 4; ++a)
#pragma unroll
        for (int b = 0; b < 4; ++b) acc[a][b] = (f32x4)(0.f);
    for (int jw = 0; jw < DD; jw += 32) {
        f32x4 vr0 = *(const f32x4*)(Ar + aoff0 + jw);
        f32x4 vr1 = *(const f32x4*)(Ar + aoff1 + jw);
        f32x4 vi0 = *(const f32x4*)(Ai + aoff0 + jw);
        f32x4 vi1 = *(const f32x4*)(Ai + aoff1 + jw);
        union { unsigned short s[4]; uint2 u; } t0, t1, t2, t3;
#pragma unroll
        for (int q = 0; q < 4; ++q) {
            t0.s[q] = f2bf(vr0[q]); t1.s[q] = f2bf(vr1[q]);
            t2.s[q] = f2bf(vi0[q]); t3.s[q] = f2bf(vi1[q]);
        }
        *(uint2*)&sAr[ brow0       * ASTR + grp * 4] = t0.u;
        *(uint2*)&sAr[(brow0 + 64) * ASTR + grp * 4] = t1.u;
        *(uint2*)&sAi[ brow0       * ASTR + grp * 4] = t2.u;
        *(uint2*)&sAi[(brow0 + 64) * ASTR + grp * 4] = t3.u;
        if (nW < UU) {
            const f32x4* kv = (const f32x4*)(Kt + (size_t)nW * DD * 2 + (size_t)(jw + jh) * 2);
#pragma unroll
            for (int q = 0; q < 8; ++q) {
                f32x4 v = kv[q];
                float wr0 = krI * v[0] - kiI * v[1], wi0 = -(krI * v[1] + kiI * v[0]);
                float wr1 = krI * v[2] - kiI * v[3], wi1 = -(krI * v[3] + kiI * v[2]);
                *(unsigned*)&sWr[nW * WSTR + jh + 2 * q] = (unsigned)f2bf(wr0) | ((unsigned)f2bf(wr1) << 16);
                *(unsigned*)&sWi[nW * WSTR + jh + 2 * q] = (unsigned)f2bf(wi0) | ((unsigned)f2bf(wi1) << 16);
            }
        } else {
#pragma unroll
            for (int q = 0; q < 8; ++q) {
                *(unsigned*)&sWr[nW * WSTR + jh + 2 * q] = 0u;
                *(unsigned*)&sWi[nW * WSTR + jh + 2 * q] = 0u;
            }
        }
        __syncthreads();
#pragma unroll
        for (int ph = 0; ph < 2; ++ph) {
            const short* sA = ph ? sAi : sAr;
            const short* sW = ph ? sWi : sWr;
            short8 af[4], bf[4];
#pragma unroll
            for (int t = 0; t < 4; ++t) {
                af[t] = *(const short8*)&sA[(mw + t * 16 + rrow) * ASTR + quad * 8];
                bf[t] = *(const short8*)&sW[(nw + t * 16 + rrow) * WSTR + quad * 8];
            }
#pragma unroll
            for (int ti = 0; ti < 4; ++ti)
#pragma unroll
                for (int tj = 0; tj < 4; ++tj)
                    acc[ti][tj] = __builtin_amdgcn_mfma_f32_16x16x32_bf16(af[ti], bf[tj], acc[ti][tj], 0, 0, 0);
        }
        __syncthreads();
    }
#pragma unroll
    for (int ti = 0; ti < 4; ++ti) {
        int m = mw + ti * 16 + quad * 4;
#pragma unroll
        for (int tj = 0; tj < 4; ++tj) {
            int n = nw + tj * 16 + rrow;
            if (n < UU)
#pragma unroll
                for (int r = 0; r < 4; ++r)
                    atomicAdd(&dst[(size_t)(m + r) * UU + n], acc[ti][tj][r]);
        }
    }
}

extern "C" void kernel_launch(void* const* d_in, const int* in_sizes, int n_in,
                              void* d_out, int out_size, void* d_ws, size_t ws_size,
                              hipStream_t stream) {
    const float* Ar = (const float*)d_in[0];
    const float* Ai = (const float*)d_in[1];
    const float* Kt = (const float*)d_in[2];
    float* out = (float*)d_out;

    const size_t kb_dwords = (size_t)NP * DD;                       // 131072
    const size_t ws_need = kb_dwords * 4 + (size_t)NWS * BB * UU * 4; // 52,133,888 B

    if (ws_size >= ws_need) {
        unsigned* Kb = (unsigned*)d_ws;
        float* ws = (float*)d_ws + kb_dwords;
        hipLaunchKernelGGL(kb_build_kernel, dim3(512), dim3(256), 0, stream, Kt, Kb);
        hipLaunchKernelGGL(zero_out_kernel, dim3(100), dim3(256), 0, stream, out);
        hipLaunchKernelGGL(cm_gemm2_kernel, dim3(DD), dim3(1024), 0, stream,
                           Ar, Ai, Kt, Kb, ws, out);
        hipLaunchKernelGGL(reduce_kernel, dim3(100, 14), dim3(256), 0, stream, ws, out);
    } else {
        hipLaunchKernelGGL(zero_out_kernel, dim3(100), dim3(256), 0, stream, out);
        hipLaunchKernelGGL(cm_gemm_fb_kernel, dim3(DD), dim3(512), 0, stream, Ar, Ai, Kt, out);
    }
}